// Round 1
// baseline (1669.734 us; speedup 1.0000x reference)
//
#include <hip/hip_runtime.h>
#include <hip/hip_bf16.h>
#include <math.h>

#define NNODES 200000
#define EDGES  65536
#define MD 128
#define TD 100
#define EDIM 128
#define XD 484           // 2*MD + TD + EDIM
#define MSGD 256
#define GD 384

// workspace layout (bytes)
#define O_COUNTS   0u                       // int[NNODES]           = 800000
#define O_NUMUPD   800000u                  // int[1]
#define O_LIST     800256u                  // int[2*EDGES]          = 524288
#define O_WTMSG    1324544u                 // float[484*256]        = 495616
#define O_WTIH     1820160u                 // float[256*384]        = 393216
#define O_WTHH     2213376u                 // float[128*384]        = 196608
#define O_MSGSUM   2410496u                 // float[NNODES*256]     = 204800000
#define WS_NEEDED  (2410496ull + 204800000ull)

__global__ __launch_bounds__(256) void k_copy(const float* __restrict__ mem,
                                              const float* __restrict__ last,
                                              float* __restrict__ out) {
    const size_t n4m = (size_t)NNODES * MD / 4;   // 6,400,000
    const size_t n4t = NNODES / 4;                // 50,000
    const float4* m4 = (const float4*)mem;
    const float4* l4 = (const float4*)last;
    float4* o4  = (float4*)out;
    float4* ot4 = (float4*)(out + (size_t)NNODES * MD);
    size_t stride = (size_t)gridDim.x * blockDim.x;
    for (size_t i = blockIdx.x * (size_t)blockDim.x + threadIdx.x; i < n4m + n4t; i += stride) {
        if (i < n4m) o4[i] = m4[i];
        else ot4[i - n4m] = l4[i - n4m];
    }
}

__global__ __launch_bounds__(256) void k_transpose(const float* __restrict__ wmsg,
                                                   const float* __restrict__ wih,
                                                   const float* __restrict__ whh,
                                                   float* __restrict__ wtmsg,
                                                   float* __restrict__ wtih,
                                                   float* __restrict__ wthh) {
    const int T1 = MSGD * XD;   // 123904
    const int T2 = GD * MSGD;   // 98304
    const int T3 = GD * MD;     // 49152
    int stride = gridDim.x * blockDim.x;
    for (int i = blockIdx.x * blockDim.x + threadIdx.x; i < T1 + T2 + T3; i += stride) {
        if (i < T1)            { int r = i / XD, k = i % XD;            wtmsg[k * MSGD + r] = wmsg[i]; }
        else if (i < T1 + T2)  { int j = i - T1; int r = j / MSGD, k = j % MSGD; wtih[k * GD + r] = wih[j]; }
        else                   { int j = i - T1 - T2; int r = j / MD,  k = j % MD;  wthh[k * GD + r] = whh[j]; }
    }
}

__global__ __launch_bounds__(256) void k_edges(const int* __restrict__ src, const int* __restrict__ dst,
                                               const float* __restrict__ ts,
                                               int* __restrict__ counts, float* __restrict__ out_ts) {
    int e = blockIdx.x * blockDim.x + threadIdx.x;
    if (e >= EDGES) return;
    int s = src[e], d = dst[e];
    unsigned tb = __float_as_uint(ts[e]);   // all ts >= 0 -> uint order == float order
    atomicAdd(&counts[s], 1);
    atomicAdd(&counts[d], 1);
    atomicMax((unsigned*)&out_ts[s], tb);
    atomicMax((unsigned*)&out_ts[d], tb);
}

__global__ __launch_bounds__(256) void k_list(const int* __restrict__ counts, int* __restrict__ numupd,
                                              int* __restrict__ list) {
    int i = blockIdx.x * blockDim.x + threadIdx.x;
    if (i >= NNODES) return;
    if (counts[i] > 0) { int p = atomicAdd(numupd, 1); list[p] = i; }
}

// 16 edge-sides per block; 256 threads: 4 side-groups (1 wave each) x 64 col-threads x 4 cols.
__global__ __launch_bounds__(256) void k_msg(const int* __restrict__ src, const int* __restrict__ dst,
                                             const float* __restrict__ ts, const float* __restrict__ ef,
                                             const float* __restrict__ mem, const float* __restrict__ last,
                                             const float* __restrict__ bf, const float* __restrict__ ph,
                                             const float* __restrict__ wt,   // [484][256]
                                             const float* __restrict__ bmsg,
                                             float* __restrict__ msgsum) {
    __shared__ float xl[16][XD];
    __shared__ int rcv[16];
    const int t = threadIdx.x;
    const int s0 = blockIdx.x * 16;

    for (int s = 0; s < 16; ++s) {
        int S = s0 + s;
        int e = (S < EDGES) ? S : S - EDGES;
        int self, other;
        if (S < EDGES) { self = src[e]; other = dst[e]; }
        else           { self = dst[e]; other = src[e]; }
        if (t == 0) rcv[s] = self;
        float dt = ts[e] - last[self];
        for (int k = t; k < XD; k += 256) {
            float v;
            if (k < MD)               v = mem[(size_t)other * MD + k];
            else if (k < 2 * MD)      v = mem[(size_t)self * MD + (k - MD)];
            else if (k < 2 * MD + TD) { int j = k - 2 * MD; v = cosf(fmaf(dt, bf[j], ph[j])); }
            else                      v = ef[(size_t)e * EDIM + (k - 2 * MD - TD)];
            xl[s][k] = v;
        }
    }
    __syncthreads();

    const int sg = t >> 6;            // wave index = side group
    const int c  = (t & 63) * 4;      // col base (256 cols total)
    float acc[4][4];
    #pragma unroll
    for (int i = 0; i < 4; ++i)
        #pragma unroll
        for (int j = 0; j < 4; ++j) acc[i][j] = 0.f;

    for (int k = 0; k < XD; k += 4) {
        float4 w0 = *(const float4*)&wt[(size_t)(k + 0) * MSGD + c];
        float4 w1 = *(const float4*)&wt[(size_t)(k + 1) * MSGD + c];
        float4 w2 = *(const float4*)&wt[(size_t)(k + 2) * MSGD + c];
        float4 w3 = *(const float4*)&wt[(size_t)(k + 3) * MSGD + c];
        #pragma unroll
        for (int i = 0; i < 4; ++i) {
            const float4 xv = *(const float4*)&xl[sg * 4 + i][k];
            acc[i][0] = fmaf(xv.x, w0.x, fmaf(xv.y, w1.x, fmaf(xv.z, w2.x, fmaf(xv.w, w3.x, acc[i][0]))));
            acc[i][1] = fmaf(xv.x, w0.y, fmaf(xv.y, w1.y, fmaf(xv.z, w2.y, fmaf(xv.w, w3.y, acc[i][1]))));
            acc[i][2] = fmaf(xv.x, w0.z, fmaf(xv.y, w1.z, fmaf(xv.z, w2.z, fmaf(xv.w, w3.z, acc[i][2]))));
            acc[i][3] = fmaf(xv.x, w0.w, fmaf(xv.y, w1.w, fmaf(xv.z, w2.w, fmaf(xv.w, w3.w, acc[i][3]))));
        }
    }

    const float4 b = *(const float4*)&bmsg[c];
    #pragma unroll
    for (int i = 0; i < 4; ++i) {
        int node = rcv[sg * 4 + i];
        float* row = &msgsum[(size_t)node * MSGD + c];
        atomicAdd(&row[0], fmaxf(acc[i][0] + b.x, 0.f));
        atomicAdd(&row[1], fmaxf(acc[i][1] + b.y, 0.f));
        atomicAdd(&row[2], fmaxf(acc[i][2] + b.z, 0.f));
        atomicAdd(&row[3], fmaxf(acc[i][3] + b.w, 0.f));
    }
}

// 16 updated nodes per block; 384 threads: 4 side-groups x 96 col-threads x 4 cols (=384 gate cols).
__global__ __launch_bounds__(384) void k_gru(const int* __restrict__ list, const int* __restrict__ numupd,
                                             const int* __restrict__ counts,
                                             const float* __restrict__ msgsum, const float* __restrict__ mem,
                                             const float* __restrict__ wtih,  // [256][384]
                                             const float* __restrict__ wthh,  // [128][384]
                                             const float* __restrict__ bih, const float* __restrict__ bhh,
                                             float* __restrict__ outmem) {
    __shared__ float gil[16][GD];
    __shared__ float ghl[16][GD];
    __shared__ int   nodesh[16];
    __shared__ float invh[16];
    const int nu = *numupd;
    const int slot0 = blockIdx.x * 16;
    if (slot0 >= nu) return;
    const int t = threadIdx.x;
    if (t < 16) {
        int slot = slot0 + t;
        int node = (slot < nu) ? list[slot] : 0;
        nodesh[t] = node;
        invh[t] = (slot < nu) ? (1.f / fmaxf((float)counts[node], 1.f)) : 0.f;
    }
    __syncthreads();

    const int ct = t % 96;
    const int sg = t / 96;
    const int c = ct * 4;
    int nd[4];
    #pragma unroll
    for (int i = 0; i < 4; ++i) nd[i] = nodesh[sg * 4 + i];

    float acc[4][4];
    #pragma unroll
    for (int i = 0; i < 4; ++i)
        #pragma unroll
        for (int j = 0; j < 4; ++j) acc[i][j] = 0.f;

    for (int k = 0; k < MSGD; k += 4) {
        float4 w0 = *(const float4*)&wtih[(size_t)(k + 0) * GD + c];
        float4 w1 = *(const float4*)&wtih[(size_t)(k + 1) * GD + c];
        float4 w2 = *(const float4*)&wtih[(size_t)(k + 2) * GD + c];
        float4 w3 = *(const float4*)&wtih[(size_t)(k + 3) * GD + c];
        #pragma unroll
        for (int i = 0; i < 4; ++i) {
            const float4 xv = *(const float4*)&msgsum[(size_t)nd[i] * MSGD + k];
            acc[i][0] = fmaf(xv.x, w0.x, fmaf(xv.y, w1.x, fmaf(xv.z, w2.x, fmaf(xv.w, w3.x, acc[i][0]))));
            acc[i][1] = fmaf(xv.x, w0.y, fmaf(xv.y, w1.y, fmaf(xv.z, w2.y, fmaf(xv.w, w3.y, acc[i][1]))));
            acc[i][2] = fmaf(xv.x, w0.z, fmaf(xv.y, w1.z, fmaf(xv.z, w2.z, fmaf(xv.w, w3.z, acc[i][2]))));
            acc[i][3] = fmaf(xv.x, w0.w, fmaf(xv.y, w1.w, fmaf(xv.z, w2.w, fmaf(xv.w, w3.w, acc[i][3]))));
        }
    }
    {
        const float4 bi = *(const float4*)&bih[c];
        #pragma unroll
        for (int i = 0; i < 4; ++i) {
            int s = sg * 4 + i;
            float inv = invh[s];
            gil[s][c + 0] = fmaf(acc[i][0], inv, bi.x);
            gil[s][c + 1] = fmaf(acc[i][1], inv, bi.y);
            gil[s][c + 2] = fmaf(acc[i][2], inv, bi.z);
            gil[s][c + 3] = fmaf(acc[i][3], inv, bi.w);
        }
    }

    #pragma unroll
    for (int i = 0; i < 4; ++i)
        #pragma unroll
        for (int j = 0; j < 4; ++j) acc[i][j] = 0.f;

    for (int k = 0; k < MD; k += 4) {
        float4 w0 = *(const float4*)&wthh[(size_t)(k + 0) * GD + c];
        float4 w1 = *(const float4*)&wthh[(size_t)(k + 1) * GD + c];
        float4 w2 = *(const float4*)&wthh[(size_t)(k + 2) * GD + c];
        float4 w3 = *(const float4*)&wthh[(size_t)(k + 3) * GD + c];
        #pragma unroll
        for (int i = 0; i < 4; ++i) {
            const float4 xv = *(const float4*)&mem[(size_t)nd[i] * MD + k];
            acc[i][0] = fmaf(xv.x, w0.x, fmaf(xv.y, w1.x, fmaf(xv.z, w2.x, fmaf(xv.w, w3.x, acc[i][0]))));
            acc[i][1] = fmaf(xv.x, w0.y, fmaf(xv.y, w1.y, fmaf(xv.z, w2.y, fmaf(xv.w, w3.y, acc[i][1]))));
            acc[i][2] = fmaf(xv.x, w0.z, fmaf(xv.y, w1.z, fmaf(xv.z, w2.z, fmaf(xv.w, w3.z, acc[i][2]))));
            acc[i][3] = fmaf(xv.x, w0.w, fmaf(xv.y, w1.w, fmaf(xv.z, w2.w, fmaf(xv.w, w3.w, acc[i][3]))));
        }
    }
    {
        const float4 bh = *(const float4*)&bhh[c];
        #pragma unroll
        for (int i = 0; i < 4; ++i) {
            int s = sg * 4 + i;
            ghl[s][c + 0] = acc[i][0] + bh.x;
            ghl[s][c + 1] = acc[i][1] + bh.y;
            ghl[s][c + 2] = acc[i][2] + bh.z;
            ghl[s][c + 3] = acc[i][3] + bh.w;
        }
    }
    __syncthreads();

    for (int idx = t; idx < 16 * MD; idx += 384) {
        int s = idx >> 7, d = idx & 127;
        if (invh[s] <= 0.f) continue;
        int node = nodesh[s];
        float ir = gil[s][d], iz = gil[s][MD + d], inn = gil[s][2 * MD + d];
        float hr = ghl[s][d], hz = ghl[s][MD + d], hn = ghl[s][2 * MD + d];
        float r  = 1.f / (1.f + __expf(-(ir + hr)));
        float z  = 1.f / (1.f + __expf(-(iz + hz)));
        float nn_ = tanhf(inn + r * hn);
        float m  = mem[(size_t)node * MD + d];
        outmem[(size_t)node * MD + d] = (1.f - z) * nn_ + z * m;
    }
}

extern "C" void kernel_launch(void* const* d_in, const int* in_sizes, int n_in,
                              void* d_out, int out_size, void* d_ws, size_t ws_size,
                              hipStream_t stream) {
    const int*   src  = (const int*)d_in[0];
    const int*   dst  = (const int*)d_in[1];
    const float* ts   = (const float*)d_in[2];
    const float* ef   = (const float*)d_in[3];
    const float* mem  = (const float*)d_in[4];
    const float* last = (const float*)d_in[5];
    const float* bf   = (const float*)d_in[6];
    const float* ph   = (const float*)d_in[7];
    const float* wmsg = (const float*)d_in[8];
    const float* bmsg = (const float*)d_in[9];
    const float* wih  = (const float*)d_in[10];
    const float* whh  = (const float*)d_in[11];
    const float* bih  = (const float*)d_in[12];
    const float* bhh  = (const float*)d_in[13];
    float* out = (float*)d_out;
    char* ws = (char*)d_ws;

    if (ws_size < WS_NEEDED) return;   // insufficient workspace -> fail loudly

    int*   counts = (int*)(ws + O_COUNTS);
    int*   numupd = (int*)(ws + O_NUMUPD);
    int*   list   = (int*)(ws + O_LIST);
    float* wtmsg  = (float*)(ws + O_WTMSG);
    float* wtih   = (float*)(ws + O_WTIH);
    float* wthh   = (float*)(ws + O_WTHH);
    float* msgsum = (float*)(ws + O_MSGSUM);
    float* out_ts = out + (size_t)NNODES * MD;

    hipMemsetAsync(ws, 0, O_WTMSG, stream);                                    // counts+numupd+list
    hipMemsetAsync(ws + O_MSGSUM, 0, (size_t)NNODES * MSGD * sizeof(float), stream);

    k_copy<<<4096, 256, 0, stream>>>(mem, last, out);
    k_transpose<<<512, 256, 0, stream>>>(wmsg, wih, whh, wtmsg, wtih, wthh);
    k_edges<<<EDGES / 256, 256, 0, stream>>>(src, dst, ts, counts, out_ts);
    k_list<<<(NNODES + 255) / 256, 256, 0, stream>>>(counts, numupd, list);
    k_msg<<<(2 * EDGES) / 16, 256, 0, stream>>>(src, dst, ts, ef, mem, last, bf, ph, wtmsg, bmsg, msgsum);
    k_gru<<<(2 * EDGES) / 16, 384, 0, stream>>>(list, numupd, counts, msgsum, mem, wtih, wthh, bih, bhh, out);
}

// Round 2
// 1094.805 us; speedup vs baseline: 1.5251x; 1.5251x over previous
//
#include <hip/hip_runtime.h>
#include <hip/hip_bf16.h>
#include <math.h>

#define NNODES 200000
#define EDGES  65536
#define MD 128
#define TD 100
#define EDIM 128
#define MSGD 256
#define GD 384
#define KX 512           // padded msg K (484 -> 512)
#define KG 384           // gru combined K (256 agg + 128 mem)

typedef __attribute__((ext_vector_type(8))) short bf16x8;
typedef __attribute__((ext_vector_type(4))) float f32x4;

// workspace layout (bytes)
#define O_COUNTS   0u                    // int[200000]
#define O_NUMUPD   800000u               // int
#define O_LIST     800256u               // int[131072]
#define O_BMSG     1324544u              // short[16*16*64*8] = 262144 B
#define O_BG       1586688u              // short[12*24*64*8] = 294912 B
#define O_BH       1881600u              // short[4*8*64*8]   = 32768 B
#define O_MSGSUM   1914368u              // float[200000*256] = 204800000 B
#define WS_NEEDED  (1914368ull + 204800000ull)

__device__ __forceinline__ short f2bf(float v) {            // RNE f32->bf16
    unsigned x = __float_as_uint(v);
    unsigned r = (x + 0x7fffu + ((x >> 16) & 1u)) >> 16;
    return (short)r;
}
__device__ __forceinline__ f32x4 mfma16(bf16x8 a, bf16x8 b, f32x4 c) {
    return __builtin_amdgcn_mfma_f32_16x16x32_bf16(a, b, c, 0, 0, 0);
}

__global__ __launch_bounds__(256) void k_copy(const float* __restrict__ mem,
                                              const float* __restrict__ last,
                                              float* __restrict__ out) {
    const size_t n4m = (size_t)NNODES * MD / 4;
    const size_t n4t = NNODES / 4;
    const float4* m4 = (const float4*)mem;
    const float4* l4 = (const float4*)last;
    float4* o4  = (float4*)out;
    float4* ot4 = (float4*)(out + (size_t)NNODES * MD);
    size_t stride = (size_t)gridDim.x * blockDim.x;
    for (size_t i = blockIdx.x * (size_t)blockDim.x + threadIdx.x; i < n4m + n4t; i += stride) {
        if (i < n4m) o4[i] = m4[i];
        else ot4[i - n4m] = l4[i - n4m];
    }
}

// pack weights into MFMA-fragment-linear bf16: frag(ks,nf) -> 64 lanes x 8 elems contiguous
// A-frag convention: lane l holds A[row=l&15][k=(l>>4)*8+j]; B: lane l holds B[k=(l>>4)*8+j][col=l&15]
__global__ __launch_bounds__(256) void k_pack(const float* __restrict__ wmsg,
                                              const float* __restrict__ wih,
                                              const float* __restrict__ whh,
                                              short* __restrict__ bmsgp,
                                              short* __restrict__ bgp,
                                              short* __restrict__ bhp) {
    const int NM = 16 * 16 * 64 * 8;   // 131072  (ks=16, nf=16) K=512, N=256
    const int NG = 12 * 24 * 64 * 8;   // 147456  (ks=12, nf=24) K=384, N=384
    const int NH = 4 * 8 * 64 * 8;     // 16384   (ks=4,  nf=8)  K=128, N=128 (n-gate cols)
    int idx = blockIdx.x * 256 + threadIdx.x;
    if (idx < NM) {
        int j = idx & 7, l = (idx >> 3) & 63, nf = (idx >> 9) & 15, ks = idx >> 13;
        int n = nf * 16 + (l & 15);
        int k = ks * 32 + ((l >> 4) << 3) + j;
        bmsgp[idx] = f2bf(k < 484 ? wmsg[n * 484 + k] : 0.f);
    } else if (idx < NM + NG) {
        int i = idx - NM;
        int j = i & 7, l = (i >> 3) & 63, rest = i >> 9;
        int nf = rest % 24, ks = rest / 24;
        int n = nf * 16 + (l & 15);
        int k = ks * 32 + ((l >> 4) << 3) + j;
        float v = (k < 256) ? wih[n * 256 + k] : whh[n * 128 + (k - 256)];
        bgp[i] = f2bf(v);
    } else if (idx < NM + NG + NH) {
        int i = idx - NM - NG;
        int j = i & 7, l = (i >> 3) & 63, rest = i >> 9;
        int nf = rest & 7, ks = rest >> 3;
        int n = 256 + nf * 16 + (l & 15);          // n-gate rows of W_hh
        int k = ks * 32 + ((l >> 4) << 3) + j;
        bhp[i] = f2bf(whh[n * 128 + k]);
    }
}

__global__ __launch_bounds__(256) void k_edges(const int* __restrict__ src, const int* __restrict__ dst,
                                               const float* __restrict__ ts,
                                               int* __restrict__ counts, float* __restrict__ out_ts) {
    int e = blockIdx.x * blockDim.x + threadIdx.x;
    if (e >= EDGES) return;
    int s = src[e], d = dst[e];
    unsigned tb = __float_as_uint(ts[e]);   // ts >= 0 -> uint order == float order
    atomicAdd(&counts[s], 1);
    atomicAdd(&counts[d], 1);
    atomicMax((unsigned*)&out_ts[s], tb);
    atomicMax((unsigned*)&out_ts[d], tb);
}

__global__ __launch_bounds__(256) void k_list(const int* __restrict__ counts, int* __restrict__ numupd,
                                              int* __restrict__ list) {
    int i = blockIdx.x * blockDim.x + threadIdx.x;
    if (i >= NNODES) return;
    if (counts[i] > 0) { int p = atomicAdd(numupd, 1); list[p] = i; }
}

// message GEMM: 64 edge-sides/block, x[64][512] bf16 in LDS (XOR-swizzled), MFMA 16x16x32.
__global__ __launch_bounds__(256) void k_msg(const int* __restrict__ src, const int* __restrict__ dst,
                                             const float* __restrict__ ts, const float* __restrict__ ef,
                                             const float* __restrict__ mem, const float* __restrict__ last,
                                             const float* __restrict__ bfq, const float* __restrict__ ph,
                                             const short* __restrict__ Bp, const float* __restrict__ bmsg,
                                             float* __restrict__ msgsum) {
    __shared__ short As[64 * KX];                 // exactly 64 KiB
    const int t = threadIdx.x;
    const int s0 = blockIdx.x * 64;

    // per-lane metadata for row (t&63); broadcast via shfl in the staging loop
    {
        const int sM = t & 63;
        const int SM = s0 + sM;
        const int eM = (SM < EDGES) ? SM : SM - EDGES;
        const int selfM  = (SM < EDGES) ? src[eM] : dst[eM];
        const int otherM = (SM < EDGES) ? dst[eM] : src[eM];
        const float dtM = ts[eM] - last[selfM];

        #pragma unroll 4
        for (int s = 0; s < 64; ++s) {
            int e     = __shfl(eM, s);
            int self  = __shfl(selfM, s);
            int other = __shfl(otherM, s);
            float dt  = __shfl(dtM, s);
            // elem 1: k = t   (other mem | self mem)
            float v1 = (t < MD) ? mem[(size_t)other * MD + t]
                                : mem[(size_t)self * MD + (t - MD)];
            // elem 2: k = 256+t  (tenc | edge feats | pad)
            int k2 = 256 + t;
            float v2;
            if (k2 < 2 * MD + TD) { int j = k2 - 2 * MD; v2 = __cosf(fmaf(dt, bfq[j], ph[j])); }
            else if (k2 < 484)    v2 = ef[(size_t)e * EDIM + (k2 - 2 * MD - TD)];
            else                  v2 = 0.f;
            int sw = (s & 7) << 3;                 // XOR swizzle in shorts (16B granules)
            As[s * KX + (t ^ sw)]         = f2bf(v1);
            As[s * KX + ((256 + t) ^ sw)] = f2bf(v2);
        }
    }
    __syncthreads();

    const int w = t >> 6, l = t & 63;
    const int lc = l & 15, lq = l >> 4;
    f32x4 acc[16];
    #pragma unroll
    for (int i = 0; i < 16; ++i) acc[i] = (f32x4){0.f, 0.f, 0.f, 0.f};

    const int r = w * 16 + lc;
    const int rbase = r * KX;
    const int rsw = (r & 7) << 3;

    for (int ks = 0; ks < 16; ++ks) {
        const bf16x8 a = *(const bf16x8*)&As[rbase + ((ks * 32 + (lq << 3)) ^ rsw)];
        const short* bp = Bp + (size_t)(ks * 16) * 512 + l * 8;
        #pragma unroll
        for (int nf = 0; nf < 16; ++nf)
            acc[nf] = mfma16(a, *(const bf16x8*)(bp + nf * 512), acc[nf]);
    }

    // epilogue: relu(acc + b) -> atomicAdd into msgsum[node]
    int nodes[4];
    #pragma unroll
    for (int jj = 0; jj < 4; ++jj) {
        int S2 = s0 + w * 16 + lq * 4 + jj;
        nodes[jj] = (S2 < EDGES) ? src[S2] : dst[S2 - EDGES];
    }
    #pragma unroll
    for (int nf = 0; nf < 16; ++nf) {
        int c = nf * 16 + lc;
        float bb = bmsg[c];
        #pragma unroll
        for (int jj = 0; jj < 4; ++jj) {
            float v = fmaxf(acc[nf][jj] + bb, 0.f);
            atomicAdd(&msgsum[(size_t)nodes[jj] * MSGD + c], v);
        }
    }
}

// GRU: 64 updated nodes/block. A = [agg(256) | mem(128)] bf16 LDS.
// accS (24 frags) = gi+gh over K=384; accH (8 frags) = h_n part over K=128 (A-frags reused).
__global__ __launch_bounds__(256) void k_gru(const int* __restrict__ list, const int* __restrict__ numupd,
                                             const int* __restrict__ counts,
                                             const float* __restrict__ msgsum, const float* __restrict__ mem,
                                             const short* __restrict__ Bg, const short* __restrict__ Bh,
                                             const float* __restrict__ bih, const float* __restrict__ bhh,
                                             float* __restrict__ outmem) {
    __shared__ short Ag[64 * KG];                 // 48 KiB
    __shared__ int   nodesh[64];
    __shared__ float invh[64];
    const int nu = *numupd;
    const int slot0 = blockIdx.x * 64;
    if (slot0 >= nu) return;
    const int t = threadIdx.x;
    if (t < 64) {
        int slot = slot0 + t;
        int node = (slot < nu) ? list[slot] : -1;
        nodesh[t] = node;
        invh[t] = (node >= 0) ? (1.f / (float)counts[node]) : 0.f;
    }
    __syncthreads();

    #pragma unroll 2
    for (int s = 0; s < 64; ++s) {
        int node = nodesh[s];
        float inv = invh[s];
        int sw = (s & 7) << 3;
        float v1 = 0.f, v2 = 0.f;
        if (node >= 0) {
            v1 = msgsum[(size_t)node * MSGD + t] * inv;
            if (t < MD) v2 = mem[(size_t)node * MD + t];
        }
        Ag[s * KG + (t ^ sw)] = f2bf(v1);
        if (t < MD) Ag[s * KG + ((256 + t) ^ sw)] = f2bf(v2);
    }
    __syncthreads();

    const int w = t >> 6, l = t & 63;
    const int lc = l & 15, lq = l >> 4;
    f32x4 accS[24];
    f32x4 accH[8];
    #pragma unroll
    for (int i = 0; i < 24; ++i) accS[i] = (f32x4){0.f, 0.f, 0.f, 0.f};
    #pragma unroll
    for (int i = 0; i < 8; ++i)  accH[i] = (f32x4){0.f, 0.f, 0.f, 0.f};

    const int r = w * 16 + lc;
    const int rbase = r * KG;
    const int rsw = (r & 7) << 3;

    for (int ks = 0; ks < 8; ++ks) {
        const bf16x8 a = *(const bf16x8*)&Ag[rbase + ((ks * 32 + (lq << 3)) ^ rsw)];
        const short* bp = Bg + (size_t)(ks * 24) * 512 + l * 8;
        #pragma unroll
        for (int nf = 0; nf < 24; ++nf)
            accS[nf] = mfma16(a, *(const bf16x8*)(bp + nf * 512), accS[nf]);
    }
    for (int ks = 8; ks < 12; ++ks) {
        const bf16x8 a = *(const bf16x8*)&Ag[rbase + ((ks * 32 + (lq << 3)) ^ rsw)];
        const short* bp = Bg + (size_t)(ks * 24) * 512 + l * 8;
        #pragma unroll
        for (int nf = 0; nf < 24; ++nf)
            accS[nf] = mfma16(a, *(const bf16x8*)(bp + nf * 512), accS[nf]);
        const short* bph = Bh + (size_t)((ks - 8) * 8) * 512 + l * 8;
        #pragma unroll
        for (int nf = 0; nf < 8; ++nf)
            accH[nf] = mfma16(a, *(const bf16x8*)(bph + nf * 512), accH[nf]);
    }

    int nd[4];
    #pragma unroll
    for (int jj = 0; jj < 4; ++jj) nd[jj] = nodesh[w * 16 + lq * 4 + jj];

    #pragma unroll
    for (int nf = 0; nf < 8; ++nf) {
        int c = nf * 16 + lc;
        float br  = bih[c] + bhh[c];
        float bz  = bih[MD + c] + bhh[MD + c];
        float bin = bih[2 * MD + c];
        float bhn = bhh[2 * MD + c];
        #pragma unroll
        for (int jj = 0; jj < 4; ++jj) {
            int node = nd[jj];
            if (node < 0) continue;
            float rr = 1.f / (1.f + expf(-(accS[nf][jj] + br)));
            float zz = 1.f / (1.f + expf(-(accS[nf + 8][jj] + bz)));
            float hn = accH[nf][jj] + bhn;                       // h_n + b_hn
            float in_ = accS[nf + 16][jj] - accH[nf][jj] + bin;  // i_n + b_in
            float nn = tanhf(in_ + rr * hn);
            float mv = mem[(size_t)node * MD + c];
            outmem[(size_t)node * MD + c] = (1.f - zz) * nn + zz * mv;
        }
    }
}

extern "C" void kernel_launch(void* const* d_in, const int* in_sizes, int n_in,
                              void* d_out, int out_size, void* d_ws, size_t ws_size,
                              hipStream_t stream) {
    const int*   src  = (const int*)d_in[0];
    const int*   dst  = (const int*)d_in[1];
    const float* ts   = (const float*)d_in[2];
    const float* ef   = (const float*)d_in[3];
    const float* mem  = (const float*)d_in[4];
    const float* last = (const float*)d_in[5];
    const float* bfq  = (const float*)d_in[6];
    const float* ph   = (const float*)d_in[7];
    const float* wmsg = (const float*)d_in[8];
    const float* bmsg = (const float*)d_in[9];
    const float* wih  = (const float*)d_in[10];
    const float* whh  = (const float*)d_in[11];
    const float* bih  = (const float*)d_in[12];
    const float* bhh  = (const float*)d_in[13];
    float* out = (float*)d_out;
    char* ws = (char*)d_ws;

    if (ws_size < WS_NEEDED) return;

    int*   counts = (int*)(ws + O_COUNTS);
    int*   numupd = (int*)(ws + O_NUMUPD);
    int*   list   = (int*)(ws + O_LIST);
    short* bmsgp  = (short*)(ws + O_BMSG);
    short* bgp    = (short*)(ws + O_BG);
    short* bhp    = (short*)(ws + O_BH);
    float* msgsum = (float*)(ws + O_MSGSUM);
    float* out_ts = out + (size_t)NNODES * MD;

    hipMemsetAsync(ws, 0, O_BMSG, stream);                                     // counts+numupd+list
    hipMemsetAsync(ws + O_MSGSUM, 0, (size_t)NNODES * MSGD * sizeof(float), stream);

    k_copy <<<4096, 256, 0, stream>>>(mem, last, out);
    k_pack <<<1152, 256, 0, stream>>>(wmsg, wih, whh, bmsgp, bgp, bhp);
    k_edges<<<EDGES / 256, 256, 0, stream>>>(src, dst, ts, counts, out_ts);
    k_list <<<(NNODES + 255) / 256, 256, 0, stream>>>(counts, numupd, list);
    k_msg  <<<(2 * EDGES) / 64, 256, 0, stream>>>(src, dst, ts, ef, mem, last, bfq, ph, bmsgp, bmsg, msgsum);
    k_gru  <<<(2 * EDGES) / 64, 256, 0, stream>>>(list, numupd, counts, msgsum, mem, bgp, bhp, bih, bhh, out);
}

// Round 3
// 439.927 us; speedup vs baseline: 3.7955x; 2.4886x over previous
//
#include <hip/hip_runtime.h>
#include <hip/hip_bf16.h>
#include <math.h>

#define NNODES 200000
#define EDGES  65536
#define NSIDES (2*EDGES)        // 131072
#define MD 128
#define TD 100
#define EDIM 128
#define MSGD 256
#define KX 512                  // padded msg K (484 -> 512)
#define KG 384                  // gru combined K (256 agg + 128 mem)
#define NSCAN 782               // ceil(200000/256)

typedef __attribute__((ext_vector_type(8))) short bf16x8;
typedef __attribute__((ext_vector_type(4))) float f32x4;

// ---- workspace layout (bytes) ----
#define O_COUNTS    0u           // int[200000] -> becomes cursor after scan3
#define O_NUMUPD    800000u      // int
#define O_BSUMC     800004u      // int[782]
#define O_BSUMF     803132u      // int[782]
#define O_UPDLIST   806272u      // int[131073]
#define O_SEGSTART  1330592u     // int[131073]
#define O_CNTLIST   1854912u     // int[131072]
#define O_BMSG      2379200u     // short[16*16*64*8] = 262144 B
#define O_BG        2641344u     // short[12*24*64*8] = 294912 B
#define O_BH        2936256u     // short[4*8*64*8]   = 32768 B
#define O_MSGBUF    2969088u     // ushort[131072*256] = 67108864 B
#define WS_NEEDED   (2969088ull + 67108864ull)

__device__ __forceinline__ short f2bf(float v) {            // RNE f32->bf16
    unsigned x = __float_as_uint(v);
    unsigned r = (x + 0x7fffu + ((x >> 16) & 1u)) >> 16;
    return (short)r;
}
__device__ __forceinline__ float bf2f(unsigned short u) {
    return __uint_as_float(((unsigned)u) << 16);
}
__device__ __forceinline__ f32x4 mfma16(bf16x8 a, bf16x8 b, f32x4 c) {
    return __builtin_amdgcn_mfma_f32_16x16x32_bf16(a, b, c, 0, 0, 0);
}

__global__ __launch_bounds__(256) void k_copy(const float* __restrict__ mem,
                                              const float* __restrict__ last,
                                              float* __restrict__ out) {
    const size_t n4m = (size_t)NNODES * MD / 4;
    const size_t n4t = NNODES / 4;
    const float4* m4 = (const float4*)mem;
    const float4* l4 = (const float4*)last;
    float4* o4  = (float4*)out;
    float4* ot4 = (float4*)(out + (size_t)NNODES * MD);
    size_t stride = (size_t)gridDim.x * blockDim.x;
    for (size_t i = blockIdx.x * (size_t)blockDim.x + threadIdx.x; i < n4m + n4t; i += stride) {
        if (i < n4m) o4[i] = m4[i];
        else ot4[i - n4m] = l4[i - n4m];
    }
}

// pack weights into MFMA-fragment-linear bf16
// A-frag: lane l holds A[row=l&15][k=(l>>4)*8+j]; B-frag: lane l holds B[k=(l>>4)*8+j][col=l&15]
__global__ __launch_bounds__(256) void k_pack(const float* __restrict__ wmsg,
                                              const float* __restrict__ wih,
                                              const float* __restrict__ whh,
                                              short* __restrict__ bmsgp,
                                              short* __restrict__ bgp,
                                              short* __restrict__ bhp) {
    const int NM = 16 * 16 * 64 * 8;   // K=512, N=256
    const int NG = 12 * 24 * 64 * 8;   // K=384, N=384
    const int NH = 4 * 8 * 64 * 8;     // K=128, N=128 (n-gate of W_hh)
    int idx = blockIdx.x * 256 + threadIdx.x;
    if (idx < NM) {
        int j = idx & 7, l = (idx >> 3) & 63, nf = (idx >> 9) & 15, ks = idx >> 13;
        int n = nf * 16 + (l & 15);
        int k = ks * 32 + ((l >> 4) << 3) + j;
        bmsgp[idx] = f2bf(k < 484 ? wmsg[n * 484 + k] : 0.f);
    } else if (idx < NM + NG) {
        int i = idx - NM;
        int j = i & 7, l = (i >> 3) & 63, rest = i >> 9;
        int nf = rest % 24, ks = rest / 24;
        int n = nf * 16 + (l & 15);
        int k = ks * 32 + ((l >> 4) << 3) + j;
        float v = (k < 256) ? wih[n * 256 + k] : whh[n * 128 + (k - 256)];
        bgp[i] = f2bf(v);
    } else if (idx < NM + NG + NH) {
        int i = idx - NM - NG;
        int j = i & 7, l = (i >> 3) & 63, rest = i >> 9;
        int nf = rest & 7, ks = rest >> 3;
        int n = 256 + nf * 16 + (l & 15);
        int k = ks * 32 + ((l >> 4) << 3) + j;
        bhp[i] = f2bf(whh[n * 128 + k]);
    }
}

__global__ __launch_bounds__(256) void k_edges(const int* __restrict__ src, const int* __restrict__ dst,
                                               const float* __restrict__ ts,
                                               int* __restrict__ counts, float* __restrict__ out_ts) {
    int e = blockIdx.x * blockDim.x + threadIdx.x;
    if (e >= EDGES) return;
    int s = src[e], d = dst[e];
    unsigned tb = __float_as_uint(ts[e]);   // ts >= 0 -> uint order == float order
    atomicAdd(&counts[s], 1);
    atomicAdd(&counts[d], 1);
    atomicMax((unsigned*)&out_ts[s], tb);
    atomicMax((unsigned*)&out_ts[d], tb);
}

__global__ __launch_bounds__(256) void k_scan1(const int* __restrict__ counts,
                                               int* __restrict__ bsumC, int* __restrict__ bsumF) {
    __shared__ int sC[256], sF[256];
    int t = threadIdx.x, i = blockIdx.x * 256 + t;
    int c = (i < NNODES) ? counts[i] : 0;
    sC[t] = c; sF[t] = (c > 0) ? 1 : 0;
    __syncthreads();
    for (int off = 128; off > 0; off >>= 1) {
        if (t < off) { sC[t] += sC[t + off]; sF[t] += sF[t + off]; }
        __syncthreads();
    }
    if (t == 0) { bsumC[blockIdx.x] = sC[0]; bsumF[blockIdx.x] = sF[0]; }
}

__global__ __launch_bounds__(1024) void k_scan2(int* __restrict__ bsumC, int* __restrict__ bsumF,
                                                int* __restrict__ numupd) {
    __shared__ int sC[1024], sF[1024];
    int t = threadIdx.x;
    int c = (t < NSCAN) ? bsumC[t] : 0;
    int f = (t < NSCAN) ? bsumF[t] : 0;
    sC[t] = c; sF[t] = f;
    __syncthreads();
    for (int off = 1; off < 1024; off <<= 1) {
        int vc = (t >= off) ? sC[t - off] : 0;
        int vf = (t >= off) ? sF[t - off] : 0;
        __syncthreads();
        sC[t] += vc; sF[t] += vf;
        __syncthreads();
    }
    if (t < NSCAN) { bsumC[t] = sC[t] - c; bsumF[t] = sF[t] - f; }  // exclusive
    if (t == 0) numupd[0] = sF[1023];
}

__global__ __launch_bounds__(256) void k_scan3(int* __restrict__ counts,   // in: counts, out: cursor
                                               const int* __restrict__ bsumC, const int* __restrict__ bsumF,
                                               int* __restrict__ updlist, int* __restrict__ segstart,
                                               int* __restrict__ cntlist, const int* __restrict__ numupd) {
    __shared__ int sC[256], sF[256];
    int t = threadIdx.x, b = blockIdx.x, i = b * 256 + t;
    int c = (i < NNODES) ? counts[i] : 0;
    int fl = (c > 0) ? 1 : 0;
    sC[t] = c; sF[t] = fl;
    __syncthreads();
    for (int off = 1; off < 256; off <<= 1) {
        int vc = (t >= off) ? sC[t - off] : 0;
        int vf = (t >= off) ? sF[t - off] : 0;
        __syncthreads();
        sC[t] += vc; sF[t] += vf;
        __syncthreads();
    }
    if (i < NNODES) {
        int segC = bsumC[b] + sC[t] - c;
        int rank = bsumF[b] + sF[t] - fl;
        if (fl) {
            updlist[rank]  = i;
            segstart[rank] = segC;
            cntlist[rank]  = c;
        }
        counts[i] = segC;                              // becomes cursor
        if (i == NNODES - 1) segstart[numupd[0]] = segC + c;   // sentinel = 131072
    }
}

// message GEMM: 32 edge-sides/block; writes bf16 msg rows at sorted positions.
__global__ __launch_bounds__(256) void k_msg(const int* __restrict__ src, const int* __restrict__ dst,
                                             const float* __restrict__ ts, const float* __restrict__ ef,
                                             const float* __restrict__ mem, const float* __restrict__ last,
                                             const float* __restrict__ bfq, const float* __restrict__ ph,
                                             const short* __restrict__ Bp, const float* __restrict__ bmsg,
                                             int* __restrict__ cursor, unsigned short* __restrict__ msgbuf) {
    __shared__ short As[32 * KX];                      // 32 KiB
    __shared__ int eS[32], selfS[32], otherS[32], posS[32];
    __shared__ float dtS[32];
    const int t = threadIdx.x;
    const int s0 = blockIdx.x * 32;

    if (t < 32) {
        int S = s0 + t;
        int e = (S < EDGES) ? S : S - EDGES;
        int self  = (S < EDGES) ? src[e] : dst[e];
        int other = (S < EDGES) ? dst[e] : src[e];
        eS[t] = e; selfS[t] = self; otherS[t] = other;
        dtS[t] = ts[e] - last[self];
        posS[t] = atomicAdd(&cursor[self], 1);
    }
    __syncthreads();

    if (t < 128) {
        #pragma unroll 4
        for (int s = 0; s < 32; ++s) {
            int sw = (s & 7) << 3;
            int other = otherS[s], self = selfS[s];
            float v1 = mem[(size_t)other * MD + t];
            float v2 = mem[(size_t)self  * MD + t];
            As[s * KX + (t ^ sw)]         = f2bf(v1);
            As[s * KX + ((128 + t) ^ sw)] = f2bf(v2);
        }
    } else {
        const int tt = t - 128;
        #pragma unroll 4
        for (int s = 0; s < 32; ++s) {
            int sw = (s & 7) << 3;
            float dt = dtS[s]; int e = eS[s];
            float va = (tt < TD) ? __cosf(fmaf(dt, bfq[tt], ph[tt]))
                                 : ef[(size_t)e * EDIM + (tt - TD)];
            float vb = (tt < TD) ? ef[(size_t)e * EDIM + (tt + 28)] : 0.f;
            As[s * KX + ((256 + tt) ^ sw)] = f2bf(va);
            As[s * KX + ((384 + tt) ^ sw)] = f2bf(vb);
        }
    }
    __syncthreads();

    const int w = t >> 6, l = t & 63, lc = l & 15, lq = l >> 4;
    const int wr = w >> 1, wc = w & 1;                 // row-tile / col-half
    f32x4 acc[8];
    #pragma unroll
    for (int i = 0; i < 8; ++i) acc[i] = (f32x4){0.f, 0.f, 0.f, 0.f};

    const int rbase = (wr * 16 + lc) * KX;
    const int rsw = (lc & 7) << 3;
    #pragma unroll 2
    for (int ks = 0; ks < 16; ++ks) {
        const bf16x8 a = *(const bf16x8*)&As[rbase + ((ks * 32 + (lq << 3)) ^ rsw)];
        const short* bp = Bp + (size_t)(ks * 16 + wc * 8) * 512 + l * 8;
        #pragma unroll
        for (int nf = 0; nf < 8; ++nf)
            acc[nf] = mfma16(a, *(const bf16x8*)(bp + nf * 512), acc[nf]);
    }

    #pragma unroll
    for (int jj = 0; jj < 4; ++jj) {
        int srow = wr * 16 + lq * 4 + jj;
        unsigned short* orow = msgbuf + (size_t)posS[srow] * MSGD;
        #pragma unroll
        for (int nf = 0; nf < 8; ++nf) {
            int c = wc * 128 + nf * 16 + lc;
            float v = fmaxf(acc[nf][jj] + bmsg[c], 0.f);
            orow[c] = (unsigned short)f2bf(v);
        }
    }
}

// GRU: 32 consecutive updated nodes/block; contiguous msgbuf span; bf16 LDS accumulate.
__global__ __launch_bounds__(256) void k_gru(const int* __restrict__ updlist, const int* __restrict__ segstart,
                                             const int* __restrict__ cntlist, const int* __restrict__ numupd,
                                             const unsigned short* __restrict__ msgbuf,
                                             const float* __restrict__ mem,
                                             const short* __restrict__ Bg, const short* __restrict__ Bh,
                                             const float* __restrict__ bih, const float* __restrict__ bhh,
                                             float* __restrict__ outmem) {
    __shared__ short Ag[32 * KG];                      // 24 KiB
    __shared__ int sb[33];
    __shared__ int nodesh[32];
    __shared__ float invh[32];
    const int nu = *numupd;
    const int slot0 = blockIdx.x * 32;
    if (slot0 >= nu) return;
    const int t = threadIdx.x;
    if (t < 33) sb[t] = segstart[min(slot0 + t, nu)];
    if (t < 32) {
        int slot = slot0 + t;
        if (slot < nu) { nodesh[t] = updlist[slot]; invh[t] = 1.f / (float)cntlist[slot]; }
        else           { nodesh[t] = -1;            invh[t] = 0.f; }
    }
    {   // zero Ag (32*384 shorts = 1536 bf16x8 chunks)
        bf16x8 z = {0, 0, 0, 0, 0, 0, 0, 0};
        #pragma unroll
        for (int i = 0; i < 6; ++i) *(bf16x8*)&Ag[(t + i * 256) * 8] = z;
    }
    __syncthreads();

    const int J0 = sb[0], J1 = sb[32];
    if (t < 128) {
        int slot = 0;
        for (int j = J0; j < J1; ++j) {
            while (j >= sb[slot + 1]) ++slot;
            unsigned u = *(const unsigned*)&msgbuf[(size_t)j * MSGD + 2 * t];
            float inv = invh[slot];
            int sw = (slot & 7) << 3;
            unsigned* p = (unsigned*)&Ag[slot * KG + ((2 * t) ^ sw)];
            unsigned a = *p;
            float alo = fmaf(__uint_as_float(u << 16),          inv, __uint_as_float(a << 16));
            float ahi = fmaf(__uint_as_float(u & 0xffff0000u), inv, __uint_as_float(a & 0xffff0000u));
            *p = ((unsigned)(unsigned short)f2bf(alo)) | (((unsigned)(unsigned short)f2bf(ahi)) << 16);
        }
    } else {
        const int tt = t - 128;
        #pragma unroll 4
        for (int s = 0; s < 32; ++s) {
            int node = nodesh[s];
            float v = (node >= 0) ? mem[(size_t)node * MD + tt] : 0.f;
            int sw = (s & 7) << 3;
            Ag[s * KG + ((256 + tt) ^ sw)] = f2bf(v);
        }
    }
    __syncthreads();

    const int w = t >> 6, l = t & 63, lc = l & 15, lq = l >> 4;
    const int wr = w >> 1, wc = w & 1;                 // row-tile / gate-channel-half
    f32x4 accS[12], accH[4];
    #pragma unroll
    for (int i = 0; i < 12; ++i) accS[i] = (f32x4){0.f, 0.f, 0.f, 0.f};
    #pragma unroll
    for (int i = 0; i < 4; ++i)  accH[i] = (f32x4){0.f, 0.f, 0.f, 0.f};

    const int rbase = (wr * 16 + lc) * KG;
    const int rsw = (lc & 7) << 3;
    #pragma unroll 2
    for (int ks = 0; ks < 12; ++ks) {
        const bf16x8 a = *(const bf16x8*)&Ag[rbase + ((ks * 32 + (lq << 3)) ^ rsw)];
        const short* bp = Bg + (size_t)(ks * 24) * 512 + l * 8;
        #pragma unroll
        for (int g = 0; g < 3; ++g)
            #pragma unroll
            for (int f = 0; f < 4; ++f)
                accS[g * 4 + f] = mfma16(a, *(const bf16x8*)(bp + (g * 8 + wc * 4 + f) * 512), accS[g * 4 + f]);
        if (ks >= 8) {
            const short* bph = Bh + (size_t)((ks - 8) * 8) * 512 + l * 8;
            #pragma unroll
            for (int f = 0; f < 4; ++f)
                accH[f] = mfma16(a, *(const bf16x8*)(bph + (wc * 4 + f) * 512), accH[f]);
        }
    }

    #pragma unroll
    for (int f = 0; f < 4; ++f) {
        int d = wc * 64 + f * 16 + lc;
        float br  = bih[d] + bhh[d];
        float bz  = bih[MD + d] + bhh[MD + d];
        float bin = bih[2 * MD + d];
        float bhn = bhh[2 * MD + d];
        #pragma unroll
        for (int jj = 0; jj < 4; ++jj) {
            int srow = wr * 16 + lq * 4 + jj;
            int node = nodesh[srow];
            if (node < 0) continue;
            float S_r = accS[f][jj] + br;
            float S_z = accS[4 + f][jj] + bz;
            float hn  = accH[f][jj] + bhn;
            float in_ = accS[8 + f][jj] - accH[f][jj] + bin;
            float rr = 1.f / (1.f + __expf(-S_r));
            float zz = 1.f / (1.f + __expf(-S_z));
            float x  = fminf(fmaxf(in_ + rr * hn, -15.f), 15.f);
            float ex = __expf(-2.f * x);
            float nn = (1.f - ex) / (1.f + ex);
            int sw = (srow & 7) << 3;
            float mv = bf2f((unsigned short)Ag[srow * KG + ((256 + d) ^ sw)]);
            outmem[(size_t)node * MD + d] = (1.f - zz) * nn + zz * mv;
        }
    }
}

extern "C" void kernel_launch(void* const* d_in, const int* in_sizes, int n_in,
                              void* d_out, int out_size, void* d_ws, size_t ws_size,
                              hipStream_t stream) {
    const int*   src  = (const int*)d_in[0];
    const int*   dst  = (const int*)d_in[1];
    const float* ts   = (const float*)d_in[2];
    const float* ef   = (const float*)d_in[3];
    const float* mem  = (const float*)d_in[4];
    const float* last = (const float*)d_in[5];
    const float* bfq  = (const float*)d_in[6];
    const float* ph   = (const float*)d_in[7];
    const float* wmsg = (const float*)d_in[8];
    const float* bmsg = (const float*)d_in[9];
    const float* wih  = (const float*)d_in[10];
    const float* whh  = (const float*)d_in[11];
    const float* bih  = (const float*)d_in[12];
    const float* bhh  = (const float*)d_in[13];
    float* out = (float*)d_out;
    char* ws = (char*)d_ws;

    if (ws_size < WS_NEEDED) return;

    int* counts   = (int*)(ws + O_COUNTS);     // -> cursor after k_scan3
    int* numupd   = (int*)(ws + O_NUMUPD);
    int* bsumC    = (int*)(ws + O_BSUMC);
    int* bsumF    = (int*)(ws + O_BSUMF);
    int* updlist  = (int*)(ws + O_UPDLIST);
    int* segstart = (int*)(ws + O_SEGSTART);
    int* cntlist  = (int*)(ws + O_CNTLIST);
    short* bmsgp  = (short*)(ws + O_BMSG);
    short* bgp    = (short*)(ws + O_BG);
    short* bhp    = (short*)(ws + O_BH);
    unsigned short* msgbuf = (unsigned short*)(ws + O_MSGBUF);
    float* out_ts = out + (size_t)NNODES * MD;

    hipMemsetAsync(ws + O_COUNTS, 0, 800004, stream);   // counts + numupd

    k_copy <<<4096, 256, 0, stream>>>(mem, last, out);
    k_pack <<<1152, 256, 0, stream>>>(wmsg, wih, whh, bmsgp, bgp, bhp);
    k_edges<<<EDGES / 256, 256, 0, stream>>>(src, dst, ts, counts, out_ts);
    k_scan1<<<NSCAN, 256, 0, stream>>>(counts, bsumC, bsumF);
    k_scan2<<<1, 1024, 0, stream>>>(bsumC, bsumF, numupd);
    k_scan3<<<NSCAN, 256, 0, stream>>>(counts, bsumC, bsumF, updlist, segstart, cntlist, numupd);
    k_msg  <<<NSIDES / 32, 256, 0, stream>>>(src, dst, ts, ef, mem, last, bfq, ph, bmsgp, bmsg, counts, msgbuf);
    k_gru  <<<NSIDES / 32, 256, 0, stream>>>(updlist, segstart, cntlist, numupd, msgbuf, mem, bgp, bhp, bih, bhh, out);
}

// Round 4
// 357.756 us; speedup vs baseline: 4.6672x; 1.2297x over previous
//
#include <hip/hip_runtime.h>
#include <hip/hip_bf16.h>
#include <math.h>

#define NNODES 200000
#define EDGES  65536
#define NSIDES (2*EDGES)        // 131072
#define MD 128
#define TD 100
#define EDIM 128
#define MSGD 256
#define KX 512                  // padded msg K (484 -> 512)
#define KG 384                  // gru combined K (256 agg + 128 mem)
#define NSCAN 782               // ceil(200000/256)
#define MBLK 64                 // k_msg rows per block

typedef __attribute__((ext_vector_type(8))) short bf16x8;
typedef __attribute__((ext_vector_type(4))) float f32x4;

// ---- workspace layout (bytes) ----
#define O_COUNTS    0u           // int[200000] -> becomes cursor after scan3
#define O_NUMUPD    800000u      // int
#define O_BSUMC     800004u      // int[782]
#define O_BSUMF     803132u      // int[782]
#define O_UPDLIST   806272u      // int[131073]
#define O_SEGSTART  1330592u     // int[131073]
#define O_CNTLIST   1854912u     // int[131072]
#define O_BMSG      2379200u     // short[16*16*64*8] = 262144 B
#define O_BG        2641344u     // short[12*24*64*8] = 294912 B
#define O_BH        2936256u     // short[4*8*64*8]   = 32768 B
#define O_MSGBUF    2969088u     // ushort[131072*256] = 67108864 B
#define WS_NEEDED   (2969088ull + 67108864ull)

__device__ __forceinline__ short f2bf(float v) {            // RNE f32->bf16
    unsigned x = __float_as_uint(v);
    unsigned r = (x + 0x7fffu + ((x >> 16) & 1u)) >> 16;
    return (short)r;
}
__device__ __forceinline__ float bflo(unsigned u) { return __uint_as_float(u << 16); }
__device__ __forceinline__ float bfhi(unsigned u) { return __uint_as_float(u & 0xffff0000u); }
__device__ __forceinline__ float bf2f(unsigned short u) {
    return __uint_as_float(((unsigned)u) << 16);
}
__device__ __forceinline__ f32x4 mfma16(bf16x8 a, bf16x8 b, f32x4 c) {
    return __builtin_amdgcn_mfma_f32_16x16x32_bf16(a, b, c, 0, 0, 0);
}

__global__ __launch_bounds__(256) void k_copy(const float* __restrict__ mem,
                                              const float* __restrict__ last,
                                              float* __restrict__ out) {
    const size_t n4m = (size_t)NNODES * MD / 4;
    const size_t n4t = NNODES / 4;
    const float4* m4 = (const float4*)mem;
    const float4* l4 = (const float4*)last;
    float4* o4  = (float4*)out;
    float4* ot4 = (float4*)(out + (size_t)NNODES * MD);
    size_t stride = (size_t)gridDim.x * blockDim.x;
    for (size_t i = blockIdx.x * (size_t)blockDim.x + threadIdx.x; i < n4m + n4t; i += stride) {
        if (i < n4m) o4[i] = m4[i];
        else ot4[i - n4m] = l4[i - n4m];
    }
}

// pack weights into MFMA-fragment-linear bf16
// A-frag: lane l holds A[row=l&15][k=(l>>4)*8+j]; B-frag: lane l holds B[k=(l>>4)*8+j][col=l&15]
__global__ __launch_bounds__(256) void k_pack(const float* __restrict__ wmsg,
                                              const float* __restrict__ wih,
                                              const float* __restrict__ whh,
                                              short* __restrict__ bmsgp,
                                              short* __restrict__ bgp,
                                              short* __restrict__ bhp) {
    const int NM = 16 * 16 * 64 * 8;   // K=512, N=256
    const int NG = 12 * 24 * 64 * 8;   // K=384, N=384
    const int NH = 4 * 8 * 64 * 8;     // K=128, N=128 (n-gate of W_hh)
    int idx = blockIdx.x * 256 + threadIdx.x;
    if (idx < NM) {
        int j = idx & 7, l = (idx >> 3) & 63, nf = (idx >> 9) & 15, ks = idx >> 13;
        int n = nf * 16 + (l & 15);
        int k = ks * 32 + ((l >> 4) << 3) + j;
        bmsgp[idx] = f2bf(k < 484 ? wmsg[n * 484 + k] : 0.f);
    } else if (idx < NM + NG) {
        int i = idx - NM;
        int j = i & 7, l = (i >> 3) & 63, rest = i >> 9;
        int nf = rest % 24, ks = rest / 24;
        int n = nf * 16 + (l & 15);
        int k = ks * 32 + ((l >> 4) << 3) + j;
        float v = (k < 256) ? wih[n * 256 + k] : whh[n * 128 + (k - 256)];
        bgp[i] = f2bf(v);
    } else if (idx < NM + NG + NH) {
        int i = idx - NM - NG;
        int j = i & 7, l = (i >> 3) & 63, rest = i >> 9;
        int nf = rest & 7, ks = rest >> 3;
        int n = 256 + nf * 16 + (l & 15);
        int k = ks * 32 + ((l >> 4) << 3) + j;
        bhp[i] = f2bf(whh[n * 128 + k]);
    }
}

__global__ __launch_bounds__(256) void k_edges(const int* __restrict__ src, const int* __restrict__ dst,
                                               const float* __restrict__ ts,
                                               int* __restrict__ counts, float* __restrict__ out_ts) {
    int e = blockIdx.x * blockDim.x + threadIdx.x;
    if (e >= EDGES) return;
    int s = src[e], d = dst[e];
    unsigned tb = __float_as_uint(ts[e]);   // ts >= 0 -> uint order == float order
    atomicAdd(&counts[s], 1);
    atomicAdd(&counts[d], 1);
    atomicMax((unsigned*)&out_ts[s], tb);
    atomicMax((unsigned*)&out_ts[d], tb);
}

__global__ __launch_bounds__(256) void k_scan1(const int* __restrict__ counts,
                                               int* __restrict__ bsumC, int* __restrict__ bsumF) {
    __shared__ int sC[256], sF[256];
    int t = threadIdx.x, i = blockIdx.x * 256 + t;
    int c = (i < NNODES) ? counts[i] : 0;
    sC[t] = c; sF[t] = (c > 0) ? 1 : 0;
    __syncthreads();
    for (int off = 128; off > 0; off >>= 1) {
        if (t < off) { sC[t] += sC[t + off]; sF[t] += sF[t + off]; }
        __syncthreads();
    }
    if (t == 0) { bsumC[blockIdx.x] = sC[0]; bsumF[blockIdx.x] = sF[0]; }
}

__global__ __launch_bounds__(1024) void k_scan2(int* __restrict__ bsumC, int* __restrict__ bsumF,
                                                int* __restrict__ numupd) {
    __shared__ int sC[1024], sF[1024];
    int t = threadIdx.x;
    int c = (t < NSCAN) ? bsumC[t] : 0;
    int f = (t < NSCAN) ? bsumF[t] : 0;
    sC[t] = c; sF[t] = f;
    __syncthreads();
    for (int off = 1; off < 1024; off <<= 1) {
        int vc = (t >= off) ? sC[t - off] : 0;
        int vf = (t >= off) ? sF[t - off] : 0;
        __syncthreads();
        sC[t] += vc; sF[t] += vf;
        __syncthreads();
    }
    if (t < NSCAN) { bsumC[t] = sC[t] - c; bsumF[t] = sF[t] - f; }  // exclusive
    if (t == 0) numupd[0] = sF[1023];
}

__global__ __launch_bounds__(256) void k_scan3(int* __restrict__ counts,   // in: counts, out: cursor
                                               const int* __restrict__ bsumC, const int* __restrict__ bsumF,
                                               int* __restrict__ updlist, int* __restrict__ segstart,
                                               int* __restrict__ cntlist, const int* __restrict__ numupd) {
    __shared__ int sC[256], sF[256];
    int t = threadIdx.x, b = blockIdx.x, i = b * 256 + t;
    int c = (i < NNODES) ? counts[i] : 0;
    int fl = (c > 0) ? 1 : 0;
    sC[t] = c; sF[t] = fl;
    __syncthreads();
    for (int off = 1; off < 256; off <<= 1) {
        int vc = (t >= off) ? sC[t - off] : 0;
        int vf = (t >= off) ? sF[t - off] : 0;
        __syncthreads();
        sC[t] += vc; sF[t] += vf;
        __syncthreads();
    }
    if (i < NNODES) {
        int segC = bsumC[b] + sC[t] - c;
        int rank = bsumF[b] + sF[t] - fl;
        if (fl) {
            updlist[rank]  = i;
            segstart[rank] = segC;
            cntlist[rank]  = c;
        }
        counts[i] = segC;                              // becomes cursor
        if (i == NNODES - 1) segstart[numupd[0]] = segC + c;   // sentinel = 131072
    }
}

// message GEMM: 64 edge-sides/block; 4 waves each own a 64-col group across all 64 rows
// (4x B-frag reuse). Writes bf16 msg rows at sorted positions.
__global__ __launch_bounds__(256) void k_msg(const int* __restrict__ src, const int* __restrict__ dst,
                                             const float* __restrict__ ts, const float* __restrict__ ef,
                                             const float* __restrict__ mem, const float* __restrict__ last,
                                             const float* __restrict__ bfq, const float* __restrict__ ph,
                                             const short* __restrict__ Bp, const float* __restrict__ bmsg,
                                             int* __restrict__ cursor, unsigned short* __restrict__ msgbuf) {
    __shared__ short As[MBLK * KX];                    // 64 KiB
    __shared__ int eS[MBLK], selfS[MBLK], otherS[MBLK], posS[MBLK];
    __shared__ float dtS[MBLK];
    const int t = threadIdx.x;
    const int s0 = blockIdx.x * MBLK;

    if (t < MBLK) {
        int S = s0 + t;
        int e = (S < EDGES) ? S : S - EDGES;
        int self  = (S < EDGES) ? src[e] : dst[e];
        int other = (S < EDGES) ? dst[e] : src[e];
        eS[t] = e; selfS[t] = self; otherS[t] = other;
        dtS[t] = ts[e] - last[self];
        posS[t] = atomicAdd(&cursor[self], 1);
    }
    __syncthreads();

    const int c4 = t & 31;          // float4 column within a row
    const int rg = t >> 5;          // row group 0..7
    // mem gather: 128 scattered row-loads, 16 independent iterations
    #pragma unroll
    for (int i = 0; i < 16; ++i) {
        int ri = rg + i * 8;        // 0..127
        int s = ri >> 1, which = ri & 1;
        int node = which ? selfS[s] : otherS[s];
        float4 v = *(const float4*)&mem[(size_t)node * MD + c4 * 4];
        int k = which * 128 + c4 * 4;
        int sw = (s & 7) << 3;
        short4 b = make_short4(f2bf(v.x), f2bf(v.y), f2bf(v.z), f2bf(v.w));
        *(short4*)&As[s * KX + (k ^ sw)] = b;
    }
    // edge feats: k = 356..483
    #pragma unroll
    for (int i = 0; i < 8; ++i) {
        int s = rg + i * 8;         // 0..63
        float4 v = *(const float4*)&ef[(size_t)eS[s] * EDIM + c4 * 4];
        int k = 356 + c4 * 4;       // mod 8 == 4 -> stays in one 8-short granule
        int sw = (s & 7) << 3;
        short4 b = make_short4(f2bf(v.x), f2bf(v.y), f2bf(v.z), f2bf(v.w));
        *(short4*)&As[s * KX + (k ^ sw)] = b;
    }
    // time encoding: k = 256..355 (wave-uniform bfq/ph index)
    {
        int s = t & 63, jg = t >> 6;
        float dt = dtS[s];
        int sw = (s & 7) << 3;
        #pragma unroll 5
        for (int j = jg * 25; j < jg * 25 + 25; ++j) {
            float v = __cosf(fmaf(dt, bfq[j], ph[j]));
            As[s * KX + ((256 + j) ^ sw)] = f2bf(v);
        }
    }
    // zero pad: k = 484..511
    {
        int s = t >> 2, p = t & 3;
        int sw = (s & 7) << 3;
        #pragma unroll
        for (int i = 0; i < 7; ++i) {
            int k = 484 + p * 7 + i;
            As[s * KX + (k ^ sw)] = 0;
        }
    }
    __syncthreads();

    const int w = t >> 6, l = t & 63, lc = l & 15, lq = l >> 4;
    f32x4 acc[4][4];                 // [row-tile][nf]
    #pragma unroll
    for (int i = 0; i < 4; ++i)
        #pragma unroll
        for (int j = 0; j < 4; ++j) acc[i][j] = (f32x4){0.f, 0.f, 0.f, 0.f};

    const int rsw = (lc & 7) << 3;
    for (int ks = 0; ks < 16; ++ks) {
        bf16x8 a[4];
        #pragma unroll
        for (int rt = 0; rt < 4; ++rt)
            a[rt] = *(const bf16x8*)&As[(rt * 16 + lc) * KX + ((ks * 32 + (lq << 3)) ^ rsw)];
        #pragma unroll
        for (int nf = 0; nf < 4; ++nf) {
            bf16x8 b = *(const bf16x8*)(Bp + (size_t)(ks * 16 + w * 4 + nf) * 512 + l * 8);
            #pragma unroll
            for (int rt = 0; rt < 4; ++rt)
                acc[rt][nf] = mfma16(a[rt], b, acc[rt][nf]);
        }
    }

    float bb[4];
    #pragma unroll
    for (int nf = 0; nf < 4; ++nf) bb[nf] = bmsg[w * 64 + nf * 16 + lc];
    #pragma unroll
    for (int rt = 0; rt < 4; ++rt) {
        #pragma unroll
        for (int jj = 0; jj < 4; ++jj) {
            int srow = rt * 16 + lq * 4 + jj;
            unsigned short* orow = msgbuf + (size_t)posS[srow] * MSGD;
            #pragma unroll
            for (int nf = 0; nf < 4; ++nf) {
                int c = w * 64 + nf * 16 + lc;
                float v = fmaxf(acc[rt][nf][jj] + bb[nf], 0.f);
                orow[c] = (unsigned short)f2bf(v);
            }
        }
    }
}

// GRU: 32 consecutive updated nodes/block; f32 register segment-sum (8 threads/slot).
__global__ __launch_bounds__(256) void k_gru(const int* __restrict__ updlist, const int* __restrict__ segstart,
                                             const int* __restrict__ cntlist, const int* __restrict__ numupd,
                                             const unsigned short* __restrict__ msgbuf,
                                             const float* __restrict__ mem,
                                             const short* __restrict__ Bg, const short* __restrict__ Bh,
                                             const float* __restrict__ bih, const float* __restrict__ bhh,
                                             float* __restrict__ outmem) {
    __shared__ short Ag[32 * KG];                      // 24 KiB
    __shared__ int sb[33];
    __shared__ int nodesh[32];
    __shared__ float invh[32];
    const int nu = *numupd;
    const int slot0 = blockIdx.x * 32;
    if (slot0 >= nu) return;
    const int t = threadIdx.x;
    if (t < 33) sb[t] = segstart[min(slot0 + t, nu)];
    if (t < 32) {
        int slot = slot0 + t;
        if (slot < nu) { nodesh[t] = updlist[slot]; invh[t] = 1.f / (float)cntlist[slot]; }
        else           { nodesh[t] = -1;            invh[t] = 0.f; }
    }
    __syncthreads();

    // mem rows -> Ag[s][256..384)
    {
        const int c4 = t & 31, rg = t >> 5;
        #pragma unroll
        for (int i = 0; i < 4; ++i) {
            int s = rg + i * 8;
            int node = nodesh[s];
            float4 v = make_float4(0.f, 0.f, 0.f, 0.f);
            if (node >= 0) v = *(const float4*)&mem[(size_t)node * MD + c4 * 4];
            int k = 256 + c4 * 4;
            int sw = (s & 7) << 3;
            short4 b = make_short4(f2bf(v.x), f2bf(v.y), f2bf(v.z), f2bf(v.w));
            *(short4*)&Ag[s * KG + (k ^ sw)] = b;
        }
    }
    // f32 register segment-sum: 8 threads per slot, 32 cols each
    {
        const int g = t >> 3, q = t & 7;
        float acc[32];
        #pragma unroll
        for (int m = 0; m < 32; ++m) acc[m] = 0.f;
        const int j0 = sb[g], j1 = sb[g + 1];
        for (int j = j0; j < j1; ++j) {
            const unsigned short* rp = msgbuf + (size_t)j * MSGD + q * 32;
            #pragma unroll
            for (int h = 0; h < 4; ++h) {
                uint4 u = *(const uint4*)(rp + h * 8);
                acc[h*8+0] += bflo(u.x); acc[h*8+1] += bfhi(u.x);
                acc[h*8+2] += bflo(u.y); acc[h*8+3] += bfhi(u.y);
                acc[h*8+4] += bflo(u.z); acc[h*8+5] += bfhi(u.z);
                acc[h*8+6] += bflo(u.w); acc[h*8+7] += bfhi(u.w);
            }
        }
        const float inv = invh[g];
        const int sw = (g & 7) << 3;
        #pragma unroll
        for (int h = 0; h < 4; ++h) {
            bf16x8 o;
            #pragma unroll
            for (int m = 0; m < 8; ++m) o[m] = f2bf(acc[h * 8 + m] * inv);
            *(bf16x8*)&Ag[g * KG + ((q * 32 + h * 8) ^ sw)] = o;
        }
    }
    __syncthreads();

    const int w = t >> 6, l = t & 63, lc = l & 15, lq = l >> 4;
    const int wr = w >> 1, wc = w & 1;                 // row-tile / gate-channel-half
    f32x4 accS[12], accH[4];
    #pragma unroll
    for (int i = 0; i < 12; ++i) accS[i] = (f32x4){0.f, 0.f, 0.f, 0.f};
    #pragma unroll
    for (int i = 0; i < 4; ++i)  accH[i] = (f32x4){0.f, 0.f, 0.f, 0.f};

    const int rbase = (wr * 16 + lc) * KG;
    const int rsw = (lc & 7) << 3;
    #pragma unroll 2
    for (int ks = 0; ks < 12; ++ks) {
        const bf16x8 a = *(const bf16x8*)&Ag[rbase + ((ks * 32 + (lq << 3)) ^ rsw)];
        const short* bp = Bg + (size_t)(ks * 24) * 512 + l * 8;
        #pragma unroll
        for (int g = 0; g < 3; ++g)
            #pragma unroll
            for (int f = 0; f < 4; ++f)
                accS[g * 4 + f] = mfma16(a, *(const bf16x8*)(bp + (g * 8 + wc * 4 + f) * 512), accS[g * 4 + f]);
        if (ks >= 8) {
            const short* bph = Bh + (size_t)((ks - 8) * 8) * 512 + l * 8;
            #pragma unroll
            for (int f = 0; f < 4; ++f)
                accH[f] = mfma16(a, *(const bf16x8*)(bph + (wc * 4 + f) * 512), accH[f]);
        }
    }

    #pragma unroll
    for (int f = 0; f < 4; ++f) {
        int d = wc * 64 + f * 16 + lc;
        float br  = bih[d] + bhh[d];
        float bz  = bih[MD + d] + bhh[MD + d];
        float bin = bih[2 * MD + d];
        float bhn = bhh[2 * MD + d];
        #pragma unroll
        for (int jj = 0; jj < 4; ++jj) {
            int srow = wr * 16 + lq * 4 + jj;
            int node = nodesh[srow];
            if (node < 0) continue;
            float S_r = accS[f][jj] + br;
            float S_z = accS[4 + f][jj] + bz;
            float hn  = accH[f][jj] + bhn;
            float in_ = accS[8 + f][jj] - accH[f][jj] + bin;
            float rr = 1.f / (1.f + __expf(-S_r));
            float zz = 1.f / (1.f + __expf(-S_z));
            float x  = fminf(fmaxf(in_ + rr * hn, -15.f), 15.f);
            float ex = __expf(-2.f * x);
            float nn = (1.f - ex) / (1.f + ex);
            int sw = (srow & 7) << 3;
            float mv = bf2f((unsigned short)Ag[srow * KG + ((256 + d) ^ sw)]);
            outmem[(size_t)node * MD + d] = (1.f - zz) * nn + zz * mv;
        }
    }
}

extern "C" void kernel_launch(void* const* d_in, const int* in_sizes, int n_in,
                              void* d_out, int out_size, void* d_ws, size_t ws_size,
                              hipStream_t stream) {
    const int*   src  = (const int*)d_in[0];
    const int*   dst  = (const int*)d_in[1];
    const float* ts   = (const float*)d_in[2];
    const float* ef   = (const float*)d_in[3];
    const float* mem  = (const float*)d_in[4];
    const float* last = (const float*)d_in[5];
    const float* bfq  = (const float*)d_in[6];
    const float* ph   = (const float*)d_in[7];
    const float* wmsg = (const float*)d_in[8];
    const float* bmsg = (const float*)d_in[9];
    const float* wih  = (const float*)d_in[10];
    const float* whh  = (const float*)d_in[11];
    const float* bih  = (const float*)d_in[12];
    const float* bhh  = (const float*)d_in[13];
    float* out = (float*)d_out;
    char* ws = (char*)d_ws;

    if (ws_size < WS_NEEDED) return;

    int* counts   = (int*)(ws + O_COUNTS);     // -> cursor after k_scan3
    int* numupd   = (int*)(ws + O_NUMUPD);
    int* bsumC    = (int*)(ws + O_BSUMC);
    int* bsumF    = (int*)(ws + O_BSUMF);
    int* updlist  = (int*)(ws + O_UPDLIST);
    int* segstart = (int*)(ws + O_SEGSTART);
    int* cntlist  = (int*)(ws + O_CNTLIST);
    short* bmsgp  = (short*)(ws + O_BMSG);
    short* bgp    = (short*)(ws + O_BG);
    short* bhp    = (short*)(ws + O_BH);
    unsigned short* msgbuf = (unsigned short*)(ws + O_MSGBUF);
    float* out_ts = out + (size_t)NNODES * MD;

    hipMemsetAsync(ws + O_COUNTS, 0, 800004, stream);   // counts + numupd

    k_copy <<<4096, 256, 0, stream>>>(mem, last, out);
    k_pack <<<1152, 256, 0, stream>>>(wmsg, wih, whh, bmsgp, bgp, bhp);
    k_edges<<<EDGES / 256, 256, 0, stream>>>(src, dst, ts, counts, out_ts);
    k_scan1<<<NSCAN, 256, 0, stream>>>(counts, bsumC, bsumF);
    k_scan2<<<1, 1024, 0, stream>>>(bsumC, bsumF, numupd);
    k_scan3<<<NSCAN, 256, 0, stream>>>(counts, bsumC, bsumF, updlist, segstart, cntlist, numupd);
    k_msg  <<<NSIDES / MBLK, 256, 0, stream>>>(src, dst, ts, ef, mem, last, bfq, ph, bmsgp, bmsg, counts, msgbuf);
    k_gru  <<<NSIDES / 32, 256, 0, stream>>>(updlist, segstart, cntlist, numupd, msgbuf, mem, bgp, bhp, bih, bhh, out);
}